// Round 9
// baseline (202.952 us; speedup 1.0000x reference)
//
#include <hip/hip_runtime.h>

#define NSET 48
#define NITEM 128
#define DIM 256
#define HEADS 4
#define NROWS (NSET * NITEM)   // 6144 rows per source

typedef _Float16 f16;
typedef _Float16 f16x8 __attribute__((ext_vector_type(8)));
typedef _Float16 f16x4 __attribute__((ext_vector_type(4)));
typedef float    f32x4 __attribute__((ext_vector_type(4)));

// ---- fragment-major layout ----
// A source matrix is stored per 128-row "set" (32768 halves = 64KB). Within a
// set: 64 chunks of 512 halves (1KB), chunk = (r/16)*8 + (k/32). Within a
// chunk, lane-slot l (16B) holds row r = rbase+(l&15), halves kbase+(l>>4)*8..+8
// -- exactly the mfma_16x16x32 A/B fragment for that (row-block, k-block).
// One operand fragment load = ONE lane-contiguous 1KB wave-load (R5 lesson:
// row-major fragment loads cost 16 L1 transactions per instruction).
#define SETH 32768   // halves per set
__device__ __forceinline__ int faddr(int r, int k) {   // in halves, within a set
  return ((r >> 4) * 8 + (k >> 5)) * 512 + ((((k >> 3) & 3) * 16 + (r & 15)) * 8) + (k & 7);
}

// ---- workspace layout (bytes) ----
static constexpr size_t OFF_XYH = 6291456;
static constexpr size_t OFF_WT  = 12582912;
static constexpr size_t OFF_LXY = 12713984;

// ---------------- prep: W transpose + fp16, frag-major ----------------
__global__ __launch_bounds__(256) void k_wt(const float* __restrict__ W,
                                            f16* __restrict__ WT_F) {
  int d = blockIdx.x, c = threadIdx.x;
  WT_F[(c >> 7) * SETH + faddr(c & 127, d)] = (f16)W[d * DIM + c];
}

// ---------------- prep: row l2-normalize + fp16 casts, frag-major ----------------
__global__ __launch_bounds__(256) void k_norm(const float* __restrict__ x,
                                              const float* __restrict__ y,
                                              f16* __restrict__ XYN_F,
                                              f16* __restrict__ XYH_F) {
  int rg   = blockIdx.x * 4 + (threadIdx.x >> 6);   // global row 0..12287
  int lane = threadIdx.x & 63;
  const float* src = (rg < NROWS) ? (x + (size_t)rg * DIM)
                                  : (y + (size_t)(rg - NROWS) * DIM);
  float4 v = *(const float4*)(src + lane * 4);
  float ss = v.x * v.x + v.y * v.y + v.z * v.z + v.w * v.w;
  #pragma unroll
  for (int off = 32; off >= 1; off >>= 1) ss += __shfl_xor(ss, off);
  float rn = 1.0f / sqrtf(fmaxf(ss, 1e-12f));       // tf.nn.l2_normalize semantics
  f16x4 hn = { (f16)(v.x * rn), (f16)(v.y * rn), (f16)(v.z * rn), (f16)(v.w * rn) };
  f16x4 hr = { (f16)v.x, (f16)v.y, (f16)v.z, (f16)v.w };
  int dst = (rg >> 7) * SETH + faddr(rg & 127, lane * 4);   // 8B slot
  *(f16x4*)(XYN_F + dst) = hn;
  *(f16x4*)(XYH_F + dst) = hr;
}

// ---------------- prep: projection GEMM  LXY[R][c] = XYH[R][:] . WT[c][:] ----------------
__global__ __launch_bounds__(256, 2) void k_proj(const f16* __restrict__ XYH_F,
                                                 const f16* __restrict__ WT_F,
                                                 f16* __restrict__ LXY_F) {
  const int bid = blockIdx.x, rt = bid >> 1, ct = bid & 1;   // 96 row-sets x 2 col-tiles
  const int tid = threadIdx.x, w = tid >> 6, lane = tid & 63;
  const int wR = (w >> 1) * 64;        // R range within set
  const int wC = (w & 1) * 64;         // c range within 128-col tile
  const int la = lane & 15, lb = lane >> 4;

  const f16* pa[4];                    // A = WT rows (c), set ct
  const f16* pb[4];                    // B = XYH rows (R), set rt
  #pragma unroll
  for (int m = 0; m < 4; ++m)
    pa[m] = WT_F + ct * SETH + ((wC >> 4) + m) * 4096 + lane * 8;
  #pragma unroll
  for (int n = 0; n < 4; ++n)
    pb[n] = XYH_F + rt * SETH + ((wR >> 4) + n) * 4096 + lane * 8;

  f32x4 acc[4][4] = {};
  #pragma unroll
  for (int k0 = 0; k0 < DIM; k0 += 32) {
    const int ko = (k0 >> 5) * 512;
    f16x8 a[4], b[4];
    #pragma unroll
    for (int m = 0; m < 4; ++m) a[m] = *(const f16x8*)(pa[m] + ko);
    #pragma unroll
    for (int n = 0; n < 4; ++n) b[n] = *(const f16x8*)(pb[n] + ko);
    #pragma unroll
    for (int m = 0; m < 4; ++m)
      #pragma unroll
      for (int n = 0; n < 4; ++n)
        acc[m][n] = __builtin_amdgcn_mfma_f32_16x16x32_f16(a[m], b[n], acc[m][n], 0, 0, 0);
  }
  // D[row=c][col=R]: lane holds 4 consecutive c at fixed R -> 8B frag-major write
  #pragma unroll
  for (int m = 0; m < 4; ++m)
    #pragma unroll
    for (int n = 0; n < 4; ++n) {
      int rloc = wR + n * 16 + la;               // R within set rt
      int c0   = ct * 128 + wC + m * 16 + lb * 4;
      f16x4 hv = { (f16)acc[m][n][0], (f16)acc[m][n][1],
                   (f16)acc[m][n][2], (f16)acc[m][n][3] };
      *(f16x4*)(LXY_F + rt * SETH + faddr(rloc, c0)) = hv;
    }
}

// ---------------- cos_sim kernel: one block per (ys,xs) ----------------
// Direct nt stores from the accumulator (no LDS): lane holds out0[i][j..j+3]
// (16B contiguous along j). n-outer/m-inner pairs the two 64B halves of each
// 128B line in back-to-back instructions. R2's direct-store "explosion" was
// spill traffic from the (256,4) reg cap, not store granularity -- split
// kernel at (256,3) has ~116 live regs < 170 cap, no spill. LDS=0.
__global__ __launch_bounds__(256, 3) void k_cos(const f16* __restrict__ XYN_F,
                                                float* __restrict__ out0) {
  const int bid = blockIdx.x;
  const int ys = bid / NSET, xs = bid % NSET;
  const int tid = threadIdx.x, w = tid >> 6, lane = tid & 63;
  const int wj = (w >> 1) * 64;        // j (y item) range -> A operand
  const int wi = (w & 1) * 64;         // i (x item) range -> B operand
  const int la = lane & 15, lb = lane >> 4;

  const f16* pa[4];
  const f16* pb[4];
  #pragma unroll
  for (int m = 0; m < 4; ++m)
    pa[m] = XYN_F + (48 + ys) * SETH + ((wj >> 4) + m) * 4096 + lane * 8;
  #pragma unroll
  for (int n = 0; n < 4; ++n)
    pb[n] = XYN_F + xs * SETH + ((wi >> 4) + n) * 4096 + lane * 8;

  f32x4 acc[4][4] = {};
  #pragma unroll
  for (int k0 = 0; k0 < DIM; k0 += 32) {
    const int ko = (k0 >> 5) * 512;
    f16x8 a[4], b[4];
    #pragma unroll
    for (int m = 0; m < 4; ++m) a[m] = *(const f16x8*)(pa[m] + ko);
    #pragma unroll
    for (int n = 0; n < 4; ++n) b[n] = *(const f16x8*)(pb[n] + ko);
    #pragma unroll
    for (int m = 0; m < 4; ++m)
      #pragma unroll
      for (int n = 0; n < 4; ++n)
        acc[m][n] = __builtin_amdgcn_mfma_f32_16x16x32_f16(a[m], b[n], acc[m][n], 0, 0, 0);
  }

  // D[row=j][col=i]; out0[ys][xs][i][j]: lane stores f32x4 at i*128+j0
  float* base = out0 + (size_t)(ys * NSET + xs) * NITEM * NITEM;
  #pragma unroll
  for (int n = 0; n < 4; ++n) {        // i blocks (outer: line halves pair on m)
    int i = wi + n * 16 + la;
    #pragma unroll
    for (int m = 0; m < 4; ++m) {      // j blocks
      int j0 = wj + m * 16 + lb * 4;
      __builtin_nontemporal_store(acc[m][n], (f32x4*)(base + (size_t)i * NITEM + j0));
    }
  }
}

// ---------------- score kernel: one block per (ys,xs) ----------------
__global__ __launch_bounds__(256, 3) void k_score(const f16* __restrict__ LXY_F,
                                                  const float* __restrict__ nItem,
                                                  const float* __restrict__ w2,
                                                  float* __restrict__ out1) {
  __shared__ float red[4][4];
  const int bid = blockIdx.x;
  const int ys = bid / NSET, xs = bid % NSET;
  const int tid = threadIdx.x, w = tid >> 6, lane = tid & 63;
  const int wj = (w >> 1) * 64;        // j (y item) range -> A operand
  const int wi = (w & 1) * 64;         // i (x item) range -> B operand

  const f16* pa[4];
  const f16* pb[4];
  #pragma unroll
  for (int m = 0; m < 4; ++m)
    pa[m] = LXY_F + (48 + ys) * SETH + ((wj >> 4) + m) * 4096 + lane * 8;
  #pragma unroll
  for (int n = 0; n < 4; ++n)
    pb[n] = LXY_F + xs * SETH + ((wi >> 4) + n) * 4096 + lane * 8;

  float rsum[HEADS];
  #pragma unroll
  for (int h = 0; h < HEADS; ++h) {
    f32x4 acc[4][4] = {};
    #pragma unroll
    for (int kk = 0; kk < 2; ++kk) {             // K=64 per head; relu AFTER full K
      const int ko = ((h * 64 + kk * 32) >> 5) * 512;
      f16x8 a[4], b[4];
      #pragma unroll
      for (int m = 0; m < 4; ++m) a[m] = *(const f16x8*)(pa[m] + ko);
      #pragma unroll
      for (int n = 0; n < 4; ++n) b[n] = *(const f16x8*)(pb[n] + ko);
      #pragma unroll
      for (int m = 0; m < 4; ++m)
        #pragma unroll
        for (int n = 0; n < 4; ++n)
          acc[m][n] = __builtin_amdgcn_mfma_f32_16x16x32_f16(a[m], b[n], acc[m][n], 0, 0, 0);
    }
    float s = 0.f;
    #pragma unroll
    for (int m = 0; m < 4; ++m)
      #pragma unroll
      for (int n = 0; n < 4; ++n)
        #pragma unroll
        for (int r = 0; r < 4; ++r) s += fmaxf(acc[m][n][r], 0.f);
    rsum[h] = s;
  }
  #pragma unroll
  for (int off = 32; off >= 1; off >>= 1)
    #pragma unroll
    for (int h = 0; h < HEADS; ++h) rsum[h] += __shfl_xor(rsum[h], off);
  if (lane == 0) {
    #pragma unroll
    for (int h = 0; h < HEADS; ++h) red[w][h] = rsum[h];
  }
  __syncthreads();
  if (tid == 0) {
    // relu(S/8) summed == (sum relu(S))/8 ; then / nItem[x] / nItem[y]; then @ w2
    float inv = 1.0f / (8.0f * nItem[xs] * nItem[ys]);
    float sc = 0.f;
    #pragma unroll
    for (int h = 0; h < HEADS; ++h)
      sc += (red[0][h] + red[1][h] + red[2][h] + red[3][h]) * inv * w2[h];
    out1[ys * NSET + xs] = sc;
  }
}

// ---------------- launch ----------------
extern "C" void kernel_launch(void* const* d_in, const int* in_sizes, int n_in,
                              void* d_out, int out_size, void* d_ws, size_t ws_size,
                              hipStream_t stream) {
  const float* x     = (const float*)d_in[0];
  const float* y     = (const float*)d_in[1];
  const float* nItem = (const float*)d_in[2];
  const float* W     = (const float*)d_in[3];
  const float* w2    = (const float*)d_in[4];
  float* out0 = (float*)d_out;
  float* out1 = out0 + (size_t)NSET * NSET * NITEM * NITEM;

  char* ws = (char*)d_ws;
  f16* XYN_F = (f16*)ws;
  f16* XYH_F = (f16*)(ws + OFF_XYH);
  f16* WT_F  = (f16*)(ws + OFF_WT);
  f16* LXY_F = (f16*)(ws + OFF_LXY);

  k_wt<<<256, 256, 0, stream>>>(W, WT_F);
  k_norm<<<(2 * NROWS) / 4, 256, 0, stream>>>(x, y, XYN_F, XYH_F);
  k_proj<<<192, 256, 0, stream>>>(XYH_F, WT_F, LXY_F);
  k_cos<<<NSET * NSET, 256, 0, stream>>>(XYN_F, out0);
  k_score<<<NSET * NSET, 256, 0, stream>>>(LXY_F, nItem, w2, out1);
}

// Round 10
// 151.115 us; speedup vs baseline: 1.3430x; 1.3430x over previous
//
#include <hip/hip_runtime.h>

#define NSET 48
#define NITEM 128
#define DIM 256
#define HEADS 4
#define NROWS (NSET * NITEM)   // 6144 rows per source
#define XPB 4                  // xs tiles per block in k_cos/k_score

typedef _Float16 f16;
typedef _Float16 f16x8 __attribute__((ext_vector_type(8)));
typedef _Float16 f16x4 __attribute__((ext_vector_type(4)));
typedef float    f32x4 __attribute__((ext_vector_type(4)));

// ---- fragment-major layout ----
// A source matrix is stored per 128-row "set" (32768 halves = 64KB). Within a
// set: 64 chunks of 512 halves (1KB), chunk = (r/16)*8 + (k/32). Within a
// chunk, lane-slot l (16B) holds row r = rbase+(l&15), halves kbase+(l>>4)*8..+8
// -- exactly the mfma_16x16x32 A/B fragment for that (row-block, k-block).
// One operand fragment load = ONE lane-contiguous 1KB wave-load (R5 lesson:
// row-major fragment loads cost 16 L1 transactions per instruction).
#define SETH 32768   // halves per set
__device__ __forceinline__ int faddr(int r, int k) {   // in halves, within a set
  return ((r >> 4) * 8 + (k >> 5)) * 512 + ((((k >> 3) & 3) * 16 + (r & 15)) * 8) + (k & 7);
}

// ---- workspace layout (bytes) ----
static constexpr size_t OFF_XYH = 6291456;
static constexpr size_t OFF_WT  = 12582912;
static constexpr size_t OFF_LXY = 12713984;

// ---------------- prep: row l2-normalize + fp16 casts + W^T (fused) ----------------
__global__ __launch_bounds__(256) void k_norm(const float* __restrict__ x,
                                              const float* __restrict__ y,
                                              const float* __restrict__ W,
                                              f16* __restrict__ XYN_F,
                                              f16* __restrict__ XYH_F,
                                              f16* __restrict__ WT_F) {
  int rg   = blockIdx.x * 4 + (threadIdx.x >> 6);   // global row 0..12287
  int lane = threadIdx.x & 63;
  const float* src = (rg < NROWS) ? (x + (size_t)rg * DIM)
                                  : (y + (size_t)(rg - NROWS) * DIM);
  float4 v = *(const float4*)(src + lane * 4);
  float ss = v.x * v.x + v.y * v.y + v.z * v.z + v.w * v.w;
  #pragma unroll
  for (int off = 32; off >= 1; off >>= 1) ss += __shfl_xor(ss, off);
  float rn = 1.0f / sqrtf(fmaxf(ss, 1e-12f));       // tf.nn.l2_normalize semantics
  f16x4 hn = { (f16)(v.x * rn), (f16)(v.y * rn), (f16)(v.z * rn), (f16)(v.w * rn) };
  f16x4 hr = { (f16)v.x, (f16)v.y, (f16)v.z, (f16)v.w };
  int dst = (rg >> 7) * SETH + faddr(rg & 127, lane * 4);   // 8B slot
  *(f16x4*)(XYN_F + dst) = hn;
  *(f16x4*)(XYH_F + dst) = hr;
  // fused W^T (saves a launch): first 256 blocks also transpose one W row
  if (blockIdx.x < 256) {
    int d = blockIdx.x, c = threadIdx.x;
    WT_F[(c >> 7) * SETH + faddr(c & 127, d)] = (f16)W[d * DIM + c];
  }
}

// ---------------- prep: projection GEMM  LXY[R][c] = XYH[R][:] . WT[c][:] ----------------
__global__ __launch_bounds__(256, 2) void k_proj(const f16* __restrict__ XYH_F,
                                                 const f16* __restrict__ WT_F,
                                                 f16* __restrict__ LXY_F) {
  const int bid = blockIdx.x, rt = bid >> 1, ct = bid & 1;   // 96 row-sets x 2 col-tiles
  const int tid = threadIdx.x, w = tid >> 6, lane = tid & 63;
  const int wR = (w >> 1) * 64;        // R range within set
  const int wC = (w & 1) * 64;         // c range within 128-col tile
  const int la = lane & 15, lb = lane >> 4;

  const f16* pa[4];                    // A = WT rows (c), set ct
  const f16* pb[4];                    // B = XYH rows (R), set rt
  #pragma unroll
  for (int m = 0; m < 4; ++m)
    pa[m] = WT_F + ct * SETH + ((wC >> 4) + m) * 4096 + lane * 8;
  #pragma unroll
  for (int n = 0; n < 4; ++n)
    pb[n] = XYH_F + rt * SETH + ((wR >> 4) + n) * 4096 + lane * 8;

  f32x4 acc[4][4] = {};
  #pragma unroll
  for (int k0 = 0; k0 < DIM; k0 += 32) {
    const int ko = (k0 >> 5) * 512;
    f16x8 a[4], b[4];
    #pragma unroll
    for (int m = 0; m < 4; ++m) a[m] = *(const f16x8*)(pa[m] + ko);
    #pragma unroll
    for (int n = 0; n < 4; ++n) b[n] = *(const f16x8*)(pb[n] + ko);
    #pragma unroll
    for (int m = 0; m < 4; ++m)
      #pragma unroll
      for (int n = 0; n < 4; ++n)
        acc[m][n] = __builtin_amdgcn_mfma_f32_16x16x32_f16(a[m], b[n], acc[m][n], 0, 0, 0);
  }
  // D[row=c][col=R]: lane holds 4 consecutive c at fixed R -> 8B frag-major write
  #pragma unroll
  for (int m = 0; m < 4; ++m)
    #pragma unroll
    for (int n = 0; n < 4; ++n) {
      int rloc = wR + n * 16 + la;               // R within set rt
      int c0   = ct * 128 + wC + m * 16 + lb * 4;
      f16x4 hv = { (f16)acc[m][n][0], (f16)acc[m][n][1],
                   (f16)acc[m][n][2], (f16)acc[m][n][3] };
      *(f16x4*)(LXY_F + rt * SETH + faddr(rloc, c0)) = hv;
    }
}

// ---------------- cos_sim kernel: one block per (ys, 4 xs) ----------------
// Direct nt stores (R9 evidence: direct-store k_cos was clean; R2-R4
// "explosions" were reg-cap spills). No LDS, no barriers -> tile t+1's
// loads/MFMA overlap tile t's store drain (no vmcnt(0) in the loop).
// 4-xs tiling: y-side fragments re-hit L1/L2 4x. (256,2): 256-reg cap, no spill.
__global__ __launch_bounds__(256, 2) void k_cos(const f16* __restrict__ XYN_F,
                                                float* __restrict__ out0) {
  const int bid = blockIdx.x;
  const int ys = bid / (NSET / XPB), xg = bid % (NSET / XPB);
  const int tid = threadIdx.x, w = tid >> 6, lane = tid & 63;
  const int wj = (w >> 1) * 64;        // j (y item) range -> A operand
  const int wi = (w & 1) * 64;         // i (x item) range -> B operand
  const int la = lane & 15, lb = lane >> 4;

  const f16* pa[4];
  #pragma unroll
  for (int m = 0; m < 4; ++m)
    pa[m] = XYN_F + (48 + ys) * SETH + ((wj >> 4) + m) * 4096 + lane * 8;

  #pragma unroll 1
  for (int t = 0; t < XPB; ++t) {
    const int xs = xg * XPB + t;
    const f16* pb[4];
    #pragma unroll
    for (int n = 0; n < 4; ++n)
      pb[n] = XYN_F + xs * SETH + ((wi >> 4) + n) * 4096 + lane * 8;

    f32x4 acc[4][4] = {};
    #pragma unroll
    for (int k0 = 0; k0 < DIM; k0 += 32) {
      const int ko = (k0 >> 5) * 512;
      f16x8 a[4], b[4];
      #pragma unroll
      for (int m = 0; m < 4; ++m) a[m] = *(const f16x8*)(pa[m] + ko);
      #pragma unroll
      for (int n = 0; n < 4; ++n) b[n] = *(const f16x8*)(pb[n] + ko);
      #pragma unroll
      for (int m = 0; m < 4; ++m)
        #pragma unroll
        for (int n = 0; n < 4; ++n)
          acc[m][n] = __builtin_amdgcn_mfma_f32_16x16x32_f16(a[m], b[n], acc[m][n], 0, 0, 0);
    }

    // D[row=j][col=i]; out0[ys][xs][i][j]: lane stores f32x4 at i*128+j0
    float* base = out0 + (size_t)(ys * NSET + xs) * NITEM * NITEM;
    #pragma unroll
    for (int n = 0; n < 4; ++n) {      // i blocks (outer: line halves pair on m)
      int i = wi + n * 16 + la;
      #pragma unroll
      for (int m = 0; m < 4; ++m) {    // j blocks
        int j0 = wj + m * 16 + lb * 4;
        __builtin_nontemporal_store(acc[m][n], (f32x4*)(base + (size_t)i * NITEM + j0));
      }
    }
  }
}

// ---------------- score kernel: one block per (ys, 4 xs) ----------------
__global__ __launch_bounds__(256, 2) void k_score(const f16* __restrict__ LXY_F,
                                                  const float* __restrict__ nItem,
                                                  const float* __restrict__ w2,
                                                  float* __restrict__ out1) {
  __shared__ float red[4][HEADS * XPB];
  const int bid = blockIdx.x;
  const int ys = bid / (NSET / XPB), xg = bid % (NSET / XPB);
  const int tid = threadIdx.x, w = tid >> 6, lane = tid & 63;
  const int wj = (w >> 1) * 64;        // j (y item) range -> A operand
  const int wi = (w & 1) * 64;         // i (x item) range -> B operand

  const f16* pa[4];
  #pragma unroll
  for (int m = 0; m < 4; ++m)
    pa[m] = LXY_F + (48 + ys) * SETH + ((wj >> 4) + m) * 4096 + lane * 8;

  float rs[XPB][HEADS];                // per-tile per-head wave-reduced sums
  #pragma unroll 1
  for (int t = 0; t < XPB; ++t) {
    const int xs = xg * XPB + t;
    const f16* pb[4];
    #pragma unroll
    for (int n = 0; n < 4; ++n)
      pb[n] = LXY_F + xs * SETH + ((wi >> 4) + n) * 4096 + lane * 8;

    #pragma unroll
    for (int h = 0; h < HEADS; ++h) {
      f32x4 acc[4][4] = {};
      #pragma unroll
      for (int kk = 0; kk < 2; ++kk) {           // K=64 per head; relu AFTER full K
        const int ko = ((h * 64 + kk * 32) >> 5) * 512;
        f16x8 a[4], b[4];
        #pragma unroll
        for (int m = 0; m < 4; ++m) a[m] = *(const f16x8*)(pa[m] + ko);
        #pragma unroll
        for (int n = 0; n < 4; ++n) b[n] = *(const f16x8*)(pb[n] + ko);
        #pragma unroll
        for (int m = 0; m < 4; ++m)
          #pragma unroll
          for (int n = 0; n < 4; ++n)
            acc[m][n] = __builtin_amdgcn_mfma_f32_16x16x32_f16(a[m], b[n], acc[m][n], 0, 0, 0);
      }
      float s = 0.f;
      #pragma unroll
      for (int m = 0; m < 4; ++m)
        #pragma unroll
        for (int n = 0; n < 4; ++n)
          #pragma unroll
          for (int r = 0; r < 4; ++r) s += fmaxf(acc[m][n][r], 0.f);
      rs[t][h] = s;
    }
  }
  #pragma unroll
  for (int off = 32; off >= 1; off >>= 1)
    #pragma unroll
    for (int t = 0; t < XPB; ++t)
      #pragma unroll
      for (int h = 0; h < HEADS; ++h) rs[t][h] += __shfl_xor(rs[t][h], off);
  if (lane == 0) {
    #pragma unroll
    for (int t = 0; t < XPB; ++t)
      #pragma unroll
      for (int h = 0; h < HEADS; ++h) red[w][t * HEADS + h] = rs[t][h];
  }
  __syncthreads();
  if (tid < XPB) {                     // thread t finalizes xs = xg*XPB + t
    int xs = xg * XPB + tid;
    float inv = 1.0f / (8.0f * nItem[xs] * nItem[ys]);
    float sc = 0.f;
    #pragma unroll
    for (int h = 0; h < HEADS; ++h)
      sc += (red[0][tid * HEADS + h] + red[1][tid * HEADS + h] +
             red[2][tid * HEADS + h] + red[3][tid * HEADS + h]) * inv * w2[h];
    out1[ys * NSET + xs] = sc;
  }
}

// ---------------- launch ----------------
extern "C" void kernel_launch(void* const* d_in, const int* in_sizes, int n_in,
                              void* d_out, int out_size, void* d_ws, size_t ws_size,
                              hipStream_t stream) {
  const float* x     = (const float*)d_in[0];
  const float* y     = (const float*)d_in[1];
  const float* nItem = (const float*)d_in[2];
  const float* W     = (const float*)d_in[3];
  const float* w2    = (const float*)d_in[4];
  float* out0 = (float*)d_out;
  float* out1 = out0 + (size_t)NSET * NSET * NITEM * NITEM;

  char* ws = (char*)d_ws;
  f16* XYN_F = (f16*)ws;
  f16* XYH_F = (f16*)(ws + OFF_XYH);
  f16* WT_F  = (f16*)(ws + OFF_WT);
  f16* LXY_F = (f16*)(ws + OFF_LXY);

  k_norm<<<(2 * NROWS) / 4, 256, 0, stream>>>(x, y, W, XYN_F, XYH_F, WT_F);
  k_proj<<<192, 256, 0, stream>>>(XYH_F, WT_F, LXY_F);
  k_cos<<<NSET * (NSET / XPB), 256, 0, stream>>>(XYN_F, out0);
  k_score<<<NSET * (NSET / XPB), 256, 0, stream>>>(LXY_F, nItem, w2, out1);
}

// Round 11
// 125.677 us; speedup vs baseline: 1.6149x; 1.2024x over previous
//
#include <hip/hip_runtime.h>

#define NSET 48
#define NITEM 128
#define DIM 256
#define HEADS 4
#define NROWS (NSET * NITEM)   // 6144 rows per source

typedef _Float16 f16;
typedef _Float16 f16x8 __attribute__((ext_vector_type(8)));
typedef _Float16 f16x4 __attribute__((ext_vector_type(4)));
typedef float    f32x4 __attribute__((ext_vector_type(4)));

// ---- fragment-major layout ----
// A source matrix is stored per 128-row "set" (32768 halves = 64KB). Within a
// set: 64 chunks of 512 halves (1KB), chunk = (r/16)*8 + (k/32). Within a
// chunk, lane-slot l (16B) holds row r = rbase+(l&15), halves kbase+(l>>4)*8..+8
// -- exactly the mfma_16x16x32 A/B fragment for that (row-block, k-block).
// One operand fragment load = ONE lane-contiguous 1KB wave-load (R5 lesson:
// row-major fragment loads cost 16 L1 transactions per instruction).
#define SETH 32768   // halves per set
__device__ __forceinline__ int faddr(int r, int k) {   // in halves, within a set
  return ((r >> 4) * 8 + (k >> 5)) * 512 + ((((k >> 3) & 3) * 16 + (r & 15)) * 8) + (k & 7);
}

// ---- workspace layout (bytes) ----
static constexpr size_t OFF_XYH = 6291456;
static constexpr size_t OFF_WT  = 12582912;
static constexpr size_t OFF_LXY = 12713984;

// ---------------- prep: row l2-normalize + fp16 casts + W^T (fused) ----------------
__global__ __launch_bounds__(256) void k_norm(const float* __restrict__ x,
                                              const float* __restrict__ y,
                                              const float* __restrict__ W,
                                              f16* __restrict__ XYN_F,
                                              f16* __restrict__ XYH_F,
                                              f16* __restrict__ WT_F) {
  int rg   = blockIdx.x * 4 + (threadIdx.x >> 6);   // global row 0..12287
  int lane = threadIdx.x & 63;
  const float* src = (rg < NROWS) ? (x + (size_t)rg * DIM)
                                  : (y + (size_t)(rg - NROWS) * DIM);
  float4 v = *(const float4*)(src + lane * 4);
  float ss = v.x * v.x + v.y * v.y + v.z * v.z + v.w * v.w;
  #pragma unroll
  for (int off = 32; off >= 1; off >>= 1) ss += __shfl_xor(ss, off);
  float rn = 1.0f / sqrtf(fmaxf(ss, 1e-12f));       // tf.nn.l2_normalize semantics
  f16x4 hn = { (f16)(v.x * rn), (f16)(v.y * rn), (f16)(v.z * rn), (f16)(v.w * rn) };
  f16x4 hr = { (f16)v.x, (f16)v.y, (f16)v.z, (f16)v.w };
  int dst = (rg >> 7) * SETH + faddr(rg & 127, lane * 4);   // 8B slot
  *(f16x4*)(XYN_F + dst) = hn;
  *(f16x4*)(XYH_F + dst) = hr;
  // fused W^T (saves a launch): first 256 blocks also transpose one W row
  if (blockIdx.x < 256) {
    int d = blockIdx.x, c = threadIdx.x;
    WT_F[(c >> 7) * SETH + faddr(c & 127, d)] = (f16)W[d * DIM + c];
  }
}

// ---------------- prep: projection GEMM  LXY[R][c] = XYH[R][:] . WT[c][:] ----------------
__global__ __launch_bounds__(256, 2) void k_proj(const f16* __restrict__ XYH_F,
                                                 const f16* __restrict__ WT_F,
                                                 f16* __restrict__ LXY_F) {
  const int bid = blockIdx.x, rt = bid >> 1, ct = bid & 1;   // 96 row-sets x 2 col-tiles
  const int tid = threadIdx.x, w = tid >> 6, lane = tid & 63;
  const int wR = (w >> 1) * 64;        // R range within set
  const int wC = (w & 1) * 64;         // c range within 128-col tile
  const int la = lane & 15, lb = lane >> 4;

  const f16* pa[4];                    // A = WT rows (c), set ct
  const f16* pb[4];                    // B = XYH rows (R), set rt
  #pragma unroll
  for (int m = 0; m < 4; ++m)
    pa[m] = WT_F + ct * SETH + ((wC >> 4) + m) * 4096 + lane * 8;
  #pragma unroll
  for (int n = 0; n < 4; ++n)
    pb[n] = XYH_F + rt * SETH + ((wR >> 4) + n) * 4096 + lane * 8;

  f32x4 acc[4][4] = {};
  #pragma unroll
  for (int k0 = 0; k0 < DIM; k0 += 32) {
    const int ko = (k0 >> 5) * 512;
    f16x8 a[4], b[4];
    #pragma unroll
    for (int m = 0; m < 4; ++m) a[m] = *(const f16x8*)(pa[m] + ko);
    #pragma unroll
    for (int n = 0; n < 4; ++n) b[n] = *(const f16x8*)(pb[n] + ko);
    #pragma unroll
    for (int m = 0; m < 4; ++m)
      #pragma unroll
      for (int n = 0; n < 4; ++n)
        acc[m][n] = __builtin_amdgcn_mfma_f32_16x16x32_f16(a[m], b[n], acc[m][n], 0, 0, 0);
  }
  // D[row=c][col=R]: lane holds 4 consecutive c at fixed R -> 8B frag-major write
  #pragma unroll
  for (int m = 0; m < 4; ++m)
    #pragma unroll
    for (int n = 0; n < 4; ++n) {
      int rloc = wR + n * 16 + la;               // R within set rt
      int c0   = ct * 128 + wC + m * 16 + lb * 4;
      f16x4 hv = { (f16)acc[m][n][0], (f16)acc[m][n][1],
                   (f16)acc[m][n][2], (f16)acc[m][n][3] };
      *(f16x4*)(LXY_F + rt * SETH + faddr(rloc, c0)) = hv;
    }
}

// ---------------- cos_sim kernel: one block per (ys,xs) ----------------
// R6 structure (2304 blocks, (256,2), frag-major reads) + direct nt stores
// from the accumulator (no LDS, no barriers). R9/R10 proved direct-store
// k_cos clean; R2-R4's "write explosion" was reg-cap spill, not stores.
__global__ __launch_bounds__(256, 2) void k_cos(const f16* __restrict__ XYN_F,
                                                float* __restrict__ out0) {
  const int bid = blockIdx.x;
  const int ys = bid / NSET, xs = bid % NSET;
  const int tid = threadIdx.x, w = tid >> 6, lane = tid & 63;
  const int wj = (w >> 1) * 64;        // j (y item) range -> A operand
  const int wi = (w & 1) * 64;         // i (x item) range -> B operand
  const int la = lane & 15, lb = lane >> 4;

  const f16* pa[4];
  const f16* pb[4];
  #pragma unroll
  for (int m = 0; m < 4; ++m)
    pa[m] = XYN_F + (48 + ys) * SETH + ((wj >> 4) + m) * 4096 + lane * 8;
  #pragma unroll
  for (int n = 0; n < 4; ++n)
    pb[n] = XYN_F + xs * SETH + ((wi >> 4) + n) * 4096 + lane * 8;

  f32x4 acc[4][4] = {};
  #pragma unroll
  for (int k0 = 0; k0 < DIM; k0 += 32) {
    const int ko = (k0 >> 5) * 512;
    f16x8 a[4], b[4];
    #pragma unroll
    for (int m = 0; m < 4; ++m) a[m] = *(const f16x8*)(pa[m] + ko);
    #pragma unroll
    for (int n = 0; n < 4; ++n) b[n] = *(const f16x8*)(pb[n] + ko);
    #pragma unroll
    for (int m = 0; m < 4; ++m)
      #pragma unroll
      for (int n = 0; n < 4; ++n)
        acc[m][n] = __builtin_amdgcn_mfma_f32_16x16x32_f16(a[m], b[n], acc[m][n], 0, 0, 0);
  }

  // D[row=j][col=i]; out0[ys][xs][i][j]: lane stores f32x4 at i*128+j0
  float* base = out0 + (size_t)(ys * NSET + xs) * NITEM * NITEM;
  #pragma unroll
  for (int n = 0; n < 4; ++n) {        // i blocks (outer: line halves pair on m)
    int i = wi + n * 16 + la;
    #pragma unroll
    for (int m = 0; m < 4; ++m) {      // j blocks
      int j0 = wj + m * 16 + lb * 4;
      __builtin_nontemporal_store(acc[m][n], (f32x4*)(base + (size_t)i * NITEM + j0));
    }
  }
}

// ---------------- score kernel: one block per (ys,xs) ---- (R6 form) ----
__global__ __launch_bounds__(256, 2) void k_score(const f16* __restrict__ LXY_F,
                                                  const float* __restrict__ nItem,
                                                  const float* __restrict__ w2,
                                                  float* __restrict__ out1) {
  __shared__ float red[4][4];
  const int bid = blockIdx.x;
  const int ys = bid / NSET, xs = bid % NSET;
  const int tid = threadIdx.x, w = tid >> 6, lane = tid & 63;
  const int wj = (w >> 1) * 64;        // j (y item) range -> A operand
  const int wi = (w & 1) * 64;         // i (x item) range -> B operand

  const f16* pa[4];
  const f16* pb[4];
  #pragma unroll
  for (int m = 0; m < 4; ++m)
    pa[m] = LXY_F + (48 + ys) * SETH + ((wj >> 4) + m) * 4096 + lane * 8;
  #pragma unroll
  for (int n = 0; n < 4; ++n)
    pb[n] = LXY_F + xs * SETH + ((wi >> 4) + n) * 4096 + lane * 8;

  float rsum[HEADS];
  #pragma unroll
  for (int h = 0; h < HEADS; ++h) {
    f32x4 acc[4][4] = {};
    #pragma unroll
    for (int kk = 0; kk < 2; ++kk) {             // K=64 per head; relu AFTER full K
      const int ko = ((h * 64 + kk * 32) >> 5) * 512;
      f16x8 a[4], b[4];
      #pragma unroll
      for (int m = 0; m < 4; ++m) a[m] = *(const f16x8*)(pa[m] + ko);
      #pragma unroll
      for (int n = 0; n < 4; ++n) b[n] = *(const f16x8*)(pb[n] + ko);
      #pragma unroll
      for (int m = 0; m < 4; ++m)
        #pragma unroll
        for (int n = 0; n < 4; ++n)
          acc[m][n] = __builtin_amdgcn_mfma_f32_16x16x32_f16(a[m], b[n], acc[m][n], 0, 0, 0);
    }
    float s = 0.f;
    #pragma unroll
    for (int m = 0; m < 4; ++m)
      #pragma unroll
      for (int n = 0; n < 4; ++n)
        #pragma unroll
        for (int r = 0; r < 4; ++r) s += fmaxf(acc[m][n][r], 0.f);
    rsum[h] = s;
  }
  #pragma unroll
  for (int off = 32; off >= 1; off >>= 1)
    #pragma unroll
    for (int h = 0; h < HEADS; ++h) rsum[h] += __shfl_xor(rsum[h], off);
  if (lane == 0) {
    #pragma unroll
    for (int h = 0; h < HEADS; ++h) red[w][h] = rsum[h];
  }
  __syncthreads();
  if (tid == 0) {
    // relu(S/8) summed == (sum relu(S))/8 ; then / nItem[x] / nItem[y]; then @ w2
    float inv = 1.0f / (8.0f * nItem[xs] * nItem[ys]);
    float sc = 0.f;
    #pragma unroll
    for (int h = 0; h < HEADS; ++h)
      sc += (red[0][h] + red[1][h] + red[2][h] + red[3][h]) * inv * w2[h];
    out1[ys * NSET + xs] = sc;
  }
}

// ---------------- launch ----------------
extern "C" void kernel_launch(void* const* d_in, const int* in_sizes, int n_in,
                              void* d_out, int out_size, void* d_ws, size_t ws_size,
                              hipStream_t stream) {
  const float* x     = (const float*)d_in[0];
  const float* y     = (const float*)d_in[1];
  const float* nItem = (const float*)d_in[2];
  const float* W     = (const float*)d_in[3];
  const float* w2    = (const float*)d_in[4];
  float* out0 = (float*)d_out;
  float* out1 = out0 + (size_t)NSET * NSET * NITEM * NITEM;

  char* ws = (char*)d_ws;
  f16* XYN_F = (f16*)ws;
  f16* XYH_F = (f16*)(ws + OFF_XYH);
  f16* WT_F  = (f16*)(ws + OFF_WT);
  f16* LXY_F = (f16*)(ws + OFF_LXY);

  k_norm<<<(2 * NROWS) / 4, 256, 0, stream>>>(x, y, W, XYN_F, XYH_F, WT_F);
  k_proj<<<192, 256, 0, stream>>>(XYH_F, WT_F, LXY_F);
  k_cos<<<NSET * NSET, 256, 0, stream>>>(XYN_F, out0);
  k_score<<<NSET * NSET, 256, 0, stream>>>(LXY_F, nItem, w2, out1);
}

// Round 12
// 117.242 us; speedup vs baseline: 1.7310x; 1.0719x over previous
//
#include <hip/hip_runtime.h>

#define NSET 48
#define NITEM 128
#define DIM 256
#define HEADS 4
#define NROWS (NSET * NITEM)   // 6144 rows per source

typedef _Float16 f16;
typedef _Float16 f16x8 __attribute__((ext_vector_type(8)));
typedef _Float16 f16x4 __attribute__((ext_vector_type(4)));
typedef float    f32x4 __attribute__((ext_vector_type(4)));

// ---- fragment-major layout ----
// A source matrix is stored per 128-row "set" (32768 halves = 64KB). Within a
// set: 64 chunks of 512 halves (1KB), chunk = (r/16)*8 + (k/32). Within a
// chunk, lane-slot l (16B) holds row r = rbase+(l&15), halves kbase+(l>>4)*8..+8
// -- exactly the mfma_16x16x32 A/B fragment for that (row-block, k-block).
// One operand fragment load = ONE lane-contiguous 1KB wave-load (R5 lesson:
// row-major fragment loads cost 16 L1 transactions per instruction).
#define SETH 32768   // halves per set
__device__ __forceinline__ int faddr(int r, int k) {   // in halves, within a set
  return ((r >> 4) * 8 + (k >> 5)) * 512 + ((((k >> 3) & 3) * 16 + (r & 15)) * 8) + (k & 7);
}

// ---- workspace layout (bytes) ----
static constexpr size_t OFF_XYH = 6291456;
static constexpr size_t OFF_WT  = 12582912;
static constexpr size_t OFF_LXY = 12713984;

// ---------------- prep: row l2-normalize + fp16 casts + W^T (fused) ----------------
__global__ __launch_bounds__(256) void k_norm(const float* __restrict__ x,
                                              const float* __restrict__ y,
                                              const float* __restrict__ W,
                                              f16* __restrict__ XYN_F,
                                              f16* __restrict__ XYH_F,
                                              f16* __restrict__ WT_F) {
  int rg   = blockIdx.x * 4 + (threadIdx.x >> 6);   // global row 0..12287
  int lane = threadIdx.x & 63;
  const float* src = (rg < NROWS) ? (x + (size_t)rg * DIM)
                                  : (y + (size_t)(rg - NROWS) * DIM);
  float4 v = *(const float4*)(src + lane * 4);
  float ss = v.x * v.x + v.y * v.y + v.z * v.z + v.w * v.w;
  #pragma unroll
  for (int off = 32; off >= 1; off >>= 1) ss += __shfl_xor(ss, off);
  float rn = 1.0f / sqrtf(fmaxf(ss, 1e-12f));       // tf.nn.l2_normalize semantics
  f16x4 hn = { (f16)(v.x * rn), (f16)(v.y * rn), (f16)(v.z * rn), (f16)(v.w * rn) };
  f16x4 hr = { (f16)v.x, (f16)v.y, (f16)v.z, (f16)v.w };
  int dst = (rg >> 7) * SETH + faddr(rg & 127, lane * 4);   // 8B slot
  *(f16x4*)(XYN_F + dst) = hn;
  *(f16x4*)(XYH_F + dst) = hr;
  // fused W^T (saves a launch): first 256 blocks also transpose one W row
  if (blockIdx.x < 256) {
    int d = blockIdx.x, c = threadIdx.x;
    WT_F[(c >> 7) * SETH + faddr(c & 127, d)] = (f16)W[d * DIM + c];
  }
}

// ---------------- prep: projection GEMM  LXY[R][c] = XYH[R][:] . WT[c][:] ----------------
__global__ __launch_bounds__(256, 2) void k_proj(const f16* __restrict__ XYH_F,
                                                 const f16* __restrict__ WT_F,
                                                 f16* __restrict__ LXY_F) {
  const int bid = blockIdx.x, rt = bid >> 1, ct = bid & 1;   // 96 row-sets x 2 col-tiles
  const int tid = threadIdx.x, w = tid >> 6, lane = tid & 63;
  const int wR = (w >> 1) * 64;        // R range within set
  const int wC = (w & 1) * 64;         // c range within 128-col tile
  const int la = lane & 15, lb = lane >> 4;

  const f16* pa[4];                    // A = WT rows (c), set ct
  const f16* pb[4];                    // B = XYH rows (R), set rt
  #pragma unroll
  for (int m = 0; m < 4; ++m)
    pa[m] = WT_F + ct * SETH + ((wC >> 4) + m) * 4096 + lane * 8;
  #pragma unroll
  for (int n = 0; n < 4; ++n)
    pb[n] = XYH_F + rt * SETH + ((wR >> 4) + n) * 4096 + lane * 8;

  f32x4 acc[4][4] = {};
  #pragma unroll
  for (int k0 = 0; k0 < DIM; k0 += 32) {
    const int ko = (k0 >> 5) * 512;
    f16x8 a[4], b[4];
    #pragma unroll
    for (int m = 0; m < 4; ++m) a[m] = *(const f16x8*)(pa[m] + ko);
    #pragma unroll
    for (int n = 0; n < 4; ++n) b[n] = *(const f16x8*)(pb[n] + ko);
    #pragma unroll
    for (int m = 0; m < 4; ++m)
      #pragma unroll
      for (int n = 0; n < 4; ++n)
        acc[m][n] = __builtin_amdgcn_mfma_f32_16x16x32_f16(a[m], b[n], acc[m][n], 0, 0, 0);
  }
  // D[row=c][col=R]: lane holds 4 consecutive c at fixed R -> 8B frag-major write
  #pragma unroll
  for (int m = 0; m < 4; ++m)
    #pragma unroll
    for (int n = 0; n < 4; ++n) {
      int rloc = wR + n * 16 + la;               // R within set rt
      int c0   = ct * 128 + wC + m * 16 + lb * 4;
      f16x4 hv = { (f16)acc[m][n][0], (f16)acc[m][n][1],
                   (f16)acc[m][n][2], (f16)acc[m][n][3] };
      *(f16x4*)(LXY_F + rt * SETH + faddr(rloc, c0)) = hv;
    }
}

// ---------------- cos_sim kernel: one 8-wave block per (ys,xs) ----------------
// R12: 512-thread blocks, per-wave tile 64x32 (acc=32 VGPR), (512,4) ->
// 128-reg cap, 2 blocks/CU = 16 waves/CU (2x the latency hiding of (256,2)).
// The big kernels are latency-bound on L2 loads (MfmaUtil 8-9%, all pipes
// idle, R5-R11); occupancy is the structural lever. Direct nt stores, no LDS.
__global__ __launch_bounds__(512, 4) void k_cos(const f16* __restrict__ XYN_F,
                                                float* __restrict__ out0) {
  const int bid = blockIdx.x;
  const int ys = bid / NSET, xs = bid % NSET;
  const int tid = threadIdx.x, w = tid >> 6, lane = tid & 63;
  const int wj = (w >> 1) * 32;        // j (y item) range -> A operand, 2 tiles
  const int wi = (w & 1) * 64;         // i (x item) range -> B operand, 4 tiles
  const int la = lane & 15, lb = lane >> 4;

  const f16* pa[2];
  const f16* pb[4];
  #pragma unroll
  for (int m = 0; m < 2; ++m)
    pa[m] = XYN_F + (48 + ys) * SETH + ((wj >> 4) + m) * 4096 + lane * 8;
  #pragma unroll
  for (int n = 0; n < 4; ++n)
    pb[n] = XYN_F + xs * SETH + ((wi >> 4) + n) * 4096 + lane * 8;

  f32x4 acc[2][4] = {};
  #pragma unroll
  for (int k0 = 0; k0 < DIM; k0 += 32) {
    const int ko = (k0 >> 5) * 512;
    f16x8 a[2], b[4];
    #pragma unroll
    for (int m = 0; m < 2; ++m) a[m] = *(const f16x8*)(pa[m] + ko);
    #pragma unroll
    for (int n = 0; n < 4; ++n) b[n] = *(const f16x8*)(pb[n] + ko);
    #pragma unroll
    for (int m = 0; m < 2; ++m)
      #pragma unroll
      for (int n = 0; n < 4; ++n)
        acc[m][n] = __builtin_amdgcn_mfma_f32_16x16x32_f16(a[m], b[n], acc[m][n], 0, 0, 0);
  }

  // D[row=j][col=i]; out0[ys][xs][i][j]: lane stores f32x4 at i*128+j0
  float* base = out0 + (size_t)(ys * NSET + xs) * NITEM * NITEM;
  #pragma unroll
  for (int n = 0; n < 4; ++n) {
    int i = wi + n * 16 + la;
    #pragma unroll
    for (int m = 0; m < 2; ++m) {
      int j0 = wj + m * 16 + lb * 4;
      __builtin_nontemporal_store(acc[m][n], (f32x4*)(base + (size_t)i * NITEM + j0));
    }
  }
}

// ---------------- score kernel: one 8-wave block per (ys,xs) ----------------
__global__ __launch_bounds__(512, 4) void k_score(const f16* __restrict__ LXY_F,
                                                  const float* __restrict__ nItem,
                                                  const float* __restrict__ w2,
                                                  float* __restrict__ out1) {
  __shared__ float red[8][HEADS];
  const int bid = blockIdx.x;
  const int ys = bid / NSET, xs = bid % NSET;
  const int tid = threadIdx.x, w = tid >> 6, lane = tid & 63;
  const int wj = (w >> 1) * 32;        // j (y item) range -> A operand, 2 tiles
  const int wi = (w & 1) * 64;         // i (x item) range -> B operand, 4 tiles

  const f16* pa[2];
  const f16* pb[4];
  #pragma unroll
  for (int m = 0; m < 2; ++m)
    pa[m] = LXY_F + (48 + ys) * SETH + ((wj >> 4) + m) * 4096 + lane * 8;
  #pragma unroll
  for (int n = 0; n < 4; ++n)
    pb[n] = LXY_F + xs * SETH + ((wi >> 4) + n) * 4096 + lane * 8;

  float rsum[HEADS];
  #pragma unroll
  for (int h = 0; h < HEADS; ++h) {
    f32x4 acc[2][4] = {};
    #pragma unroll
    for (int kk = 0; kk < 2; ++kk) {             // K=64 per head; relu AFTER full K
      const int ko = (h * 2 + kk) * 512;
      f16x8 a[2], b[4];
      #pragma unroll
      for (int m = 0; m < 2; ++m) a[m] = *(const f16x8*)(pa[m] + ko);
      #pragma unroll
      for (int n = 0; n < 4; ++n) b[n] = *(const f16x8*)(pb[n] + ko);
      #pragma unroll
      for (int m = 0; m < 2; ++m)
        #pragma unroll
        for (int n = 0; n < 4; ++n)
          acc[m][n] = __builtin_amdgcn_mfma_f32_16x16x32_f16(a[m], b[n], acc[m][n], 0, 0, 0);
    }
    float s = 0.f;
    #pragma unroll
    for (int m = 0; m < 2; ++m)
      #pragma unroll
      for (int n = 0; n < 4; ++n)
        #pragma unroll
        for (int r = 0; r < 4; ++r) s += fmaxf(acc[m][n][r], 0.f);
    rsum[h] = s;
  }
  #pragma unroll
  for (int off = 32; off >= 1; off >>= 1)
    #pragma unroll
    for (int h = 0; h < HEADS; ++h) rsum[h] += __shfl_xor(rsum[h], off);
  if (lane == 0) {
    #pragma unroll
    for (int h = 0; h < HEADS; ++h) red[w][h] = rsum[h];
  }
  __syncthreads();
  if (tid == 0) {
    // relu(S/8) summed == (sum relu(S))/8 ; then / nItem[x] / nItem[y]; then @ w2
    float inv = 1.0f / (8.0f * nItem[xs] * nItem[ys]);
    float sc = 0.f;
    #pragma unroll
    for (int h = 0; h < HEADS; ++h) {
      float t = 0.f;
      #pragma unroll
      for (int ww = 0; ww < 8; ++ww) t += red[ww][h];
      sc += t * inv * w2[h];
    }
    out1[ys * NSET + xs] = sc;
  }
}

// ---------------- launch ----------------
extern "C" void kernel_launch(void* const* d_in, const int* in_sizes, int n_in,
                              void* d_out, int out_size, void* d_ws, size_t ws_size,
                              hipStream_t stream) {
  const float* x     = (const float*)d_in[0];
  const float* y     = (const float*)d_in[1];
  const float* nItem = (const float*)d_in[2];
  const float* W     = (const float*)d_in[3];
  const float* w2    = (const float*)d_in[4];
  float* out0 = (float*)d_out;
  float* out1 = out0 + (size_t)NSET * NSET * NITEM * NITEM;

  char* ws = (char*)d_ws;
  f16* XYN_F = (f16*)ws;
  f16* XYH_F = (f16*)(ws + OFF_XYH);
  f16* WT_F  = (f16*)(ws + OFF_WT);
  f16* LXY_F = (f16*)(ws + OFF_LXY);

  k_norm<<<(2 * NROWS) / 4, 256, 0, stream>>>(x, y, W, XYN_F, XYH_F, WT_F);
  k_proj<<<192, 256, 0, stream>>>(XYH_F, WT_F, LXY_F);
  k_cos<<<NSET * NSET, 512, 0, stream>>>(XYN_F, out0);
  k_score<<<NSET * NSET, 512, 0, stream>>>(LXY_F, nItem, w2, out1);
}